// Round 2
// baseline (677.652 us; speedup 1.0000x reference)
//
#include <hip/hip_runtime.h>
#include <math.h>

// Problem constants (fixed by reference setup_inputs)
#define E_ 4
#define L_ 10
#define S_ 1024
#define F_ 256
#define T_ 1024
#define NROW (E_*L_*S_)          // 40960 rows of the GEMM
#define KPAD 512                 // max conv half-support (padding)
#define NPAD (KPAD + T_ + KPAD + 8)   // 2056 floats per padded w-plane
#define GS_HALF 512
#define GS_LEN 1040              // symmetric tap table, zero-padded

// workspace layout (float indices)
#define OFF_GS   32
#define OFF_ET   2048
#define OFF_M    4096
#define OFF_W    (4096 + (size_t)NROW * F_)

__device__ __forceinline__ unsigned int encf(float x) {
  unsigned int b = __float_as_uint(x);
  return (b & 0x80000000u) ? ~b : (b | 0x80000000u);
}
__device__ __forceinline__ float decf(unsigned int u) {
  unsigned int b = (u & 0x80000000u) ? (u ^ 0x80000000u) : ~u;
  return __uint_as_float(b);
}
__device__ __forceinline__ void fma4(float4& c, float s, const float4& p) {
  c.x = fmaf(s, p.x, c.x); c.y = fmaf(s, p.y, c.y);
  c.z = fmaf(s, p.z, c.z); c.w = fmaf(s, p.w, c.w);
}

// K0: m = matrix @ params (fp32), layout unchanged (e,l,s,f); fused global min/max.
// P staged in LDS in 64-row chunks (64 KB). Wave handles 16 rows; A loads are
// wave-uniform -> scalar loads. Thread: 16 rows x 4 g (float4 acc), acc lives
// across the 4 P-chunks.
__global__ __launch_bounds__(256) void k0_gemm(const float* __restrict__ A,
                                               const float* __restrict__ P,
                                               float* __restrict__ M,
                                               unsigned int* __restrict__ slots) {
  __shared__ __align__(16) float Pl[64 * F_];   // 64 KB
  const int tid = threadIdx.x;
  const int lane = tid & 63;
  const int wv = __builtin_amdgcn_readfirstlane(tid >> 6);
  const int row0 = blockIdx.x * 64 + wv * 16;
  const int g4 = lane * 4;
  float4 acc[16];
#pragma unroll
  for (int r = 0; r < 16; ++r) acc[r] = make_float4(0.f, 0.f, 0.f, 0.f);
  for (int fc = 0; fc < F_; fc += 64) {
    __syncthreads();
    {
      const float4* Ps = (const float4*)(P + (size_t)fc * F_);
      float4* Pd = (float4*)Pl;
      for (int i = tid; i < 64 * F_ / 4; i += 256) Pd[i] = Ps[i];
    }
    __syncthreads();
    for (int f0 = 0; f0 < 64; f0 += 4) {
      float4 p0 = *(const float4*)&Pl[(f0 + 0) * F_ + g4];
      float4 p1 = *(const float4*)&Pl[(f0 + 1) * F_ + g4];
      float4 p2 = *(const float4*)&Pl[(f0 + 2) * F_ + g4];
      float4 p3 = *(const float4*)&Pl[(f0 + 3) * F_ + g4];
#pragma unroll
      for (int r = 0; r < 16; ++r) {
        float4 a = *(const float4*)&A[(size_t)(row0 + r) * F_ + fc + f0]; // uniform
        fma4(acc[r], a.x, p0); fma4(acc[r], a.y, p1);
        fma4(acc[r], a.z, p2); fma4(acc[r], a.w, p3);
      }
    }
  }
  float vmin = 3.4e38f, vmax = -3.4e38f;
#pragma unroll
  for (int r = 0; r < 16; ++r) {
    *(float4*)&M[(size_t)(row0 + r) * F_ + g4] = acc[r];
    vmin = fminf(vmin, fminf(fminf(acc[r].x, acc[r].y), fminf(acc[r].z, acc[r].w)));
    vmax = fmaxf(vmax, fmaxf(fmaxf(acc[r].x, acc[r].y), fmaxf(acc[r].z, acc[r].w)));
  }
#pragma unroll
  for (int off = 32; off; off >>= 1) {
    vmin = fminf(vmin, __shfl_down(vmin, off));
    vmax = fmaxf(vmax, __shfl_down(vmax, off));
  }
  if (lane == 0) {
    atomicMin(&slots[0], encf(vmin));
    atomicMax(&slots[1], encf(vmax));
  }
}

// K1: grid constants + symmetric zero-padded Gaussian tap table + exp(c*x_t^2) table.
__global__ __launch_bounds__(256) void k1_setup(const unsigned int* __restrict__ slots,
                                                float* __restrict__ hdr,
                                                int* __restrict__ hdri,
                                                float* __restrict__ Gs,
                                                float* __restrict__ et) {
  const float left = decf(slots[0]);
  const float right = decf(slots[1]);
  const float dg = (right - left) / 1023.0f;    // linspace step (1024 pts)
  const float inv_dg = 1.0f / dg;
  const float delta = (right - left) / 1024.0f; // reference's delta
  const float divisor = 0.62665706865775006f;   // sqrt(2*pi)*0.25
  const float scale = delta * 0.5f / divisor;
  int kmax = (int)(2.39792f * inv_dg) + 1;      // exp(-8u^2)<1e-20 beyond
  if (kmax > KPAD - 8) kmax = KPAD - 8;
  const int K4 = (kmax + 4) & ~3;
  const int tid = threadIdx.x;
  if (tid == 0) {
    hdr[0] = left; hdr[1] = dg; hdr[2] = inv_dg; hdr[3] = scale;
    hdri[4] = K4;
  }
  const float c = -8.0f;
  for (int j = tid; j < GS_LEN; j += 256) {
    int k = j - GS_HALF;
    int ak = k < 0 ? -k : k;
    float u = (float)k * dg;
    Gs[j] = (ak <= kmax) ? expf(c * u * u) : 0.0f;
  }
  for (int t = tid; t < T_; t += 256) {
    float x = left + (float)t * dg;
    et[t] = expf(c * x * x);
  }
}

// K2: linear binning. Block = (e,l) x 16-column group; 16x1024 fp32 bins in LDS.
__global__ __launch_bounds__(256) void k2_bin(const float* __restrict__ M,
                                              const float* __restrict__ hdr,
                                              float* __restrict__ wbuf) {
  __shared__ float wl[16][T_];   // 64 KB
  const int tid = threadIdx.x;
  const int el = blockIdx.x >> 4;
  const int fg = blockIdx.x & 15;
  {
    float4* z = (float4*)&wl[0][0];
    for (int i = tid; i < 16 * T_ / 4; i += 256) z[i] = make_float4(0.f, 0.f, 0.f, 0.f);
  }
  __syncthreads();
  const float left = hdr[0];
  const float inv_dg = hdr[2];
  const int fs = tid & 15;
  const int ss = tid >> 4;
  const float* base = M + (size_t)el * S_ * F_ + fg * 16 + fs;
  for (int s = ss; s < S_; s += 16) {
    float v = base[(size_t)s * F_];
    float p = (v - left) * inv_dg;
    int j = (int)p;
    if (j > 1022) j = 1022;
    float a = p - (float)j;
    atomicAdd(&wl[fs][j], 1.0f - a);
    atomicAdd(&wl[fs][j + 1], a);
  }
  __syncthreads();
  float* out = wbuf + ((size_t)el * F_ + fg * 16) * T_;
  const float* src = (const float*)wl;
  for (int i = tid; i < 16 * T_; i += 256) out[i] = src[i];
}

// K3: per-(l,f) block: 4 zero-padded w-planes in LDS, convolution with register
// sliding window (t = 8*tid + dt), fused zero-correction, 6 pair |diff| sums,
// shuffle+LDS reduction, train/test max epilogue.
__global__ __launch_bounds__(128) void k3_conv(const float* __restrict__ wbuf,
                                               const float* __restrict__ Gs,
                                               const float* __restrict__ et,
                                               const float* __restrict__ hdr,
                                               const int* __restrict__ hdri,
                                               const float* __restrict__ dl,
                                               float* __restrict__ out) {
  __shared__ __align__(16) float wpad[E_][NPAD];  // ~32.9 KB
  __shared__ float rs[2][6];
  const int tid = threadIdx.x;
  const int l = blockIdx.x >> 8;
  const int f = blockIdx.x & 255;
  {
    float4* z = (float4*)&wpad[0][0];
    const int n4 = E_ * NPAD / 4;
    for (int i = tid; i < n4; i += 128) z[i] = make_float4(0.f, 0.f, 0.f, 0.f);
  }
  __syncthreads();
#pragma unroll
  for (int e = 0; e < E_; ++e) {
    const float4* src = (const float4*)(wbuf + ((size_t)(e * L_ + l) * F_ + f) * T_);
    float4 v0 = src[2 * tid];
    float4 v1 = src[2 * tid + 1];
    *(float4*)&wpad[e][KPAD + 8 * tid] = v0;
    *(float4*)&wpad[e][KPAD + 8 * tid + 4] = v1;
  }
  __syncthreads();
  const int K4 = hdri[4];
  const float scale = hdr[3];
  const int base = KPAD + 8 * tid;
  float acc[E_][8];
#pragma unroll
  for (int e = 0; e < E_; ++e)
#pragma unroll
    for (int d = 0; d < 8; ++d) acc[e][d] = 0.f;
  float4 A0[E_], A1[E_];
#pragma unroll
  for (int e = 0; e < E_; ++e) {
    A0[e] = *(const float4*)&wpad[e][base - K4];
    A1[e] = *(const float4*)&wpad[e][base - K4 + 4];
  }
  for (int k0 = -K4; k0 < K4; k0 += 4) {
    const float4 g4 = *(const float4*)(Gs + GS_HALF + k0);  // uniform -> s_load
#pragma unroll
    for (int e = 0; e < E_; ++e) {
      float4 A2 = *(const float4*)&wpad[e][base + k0 + 8];
      float W[12] = {A0[e].x, A0[e].y, A0[e].z, A0[e].w,
                     A1[e].x, A1[e].y, A1[e].z, A1[e].w,
                     A2.x,    A2.y,    A2.z,    A2.w};
#pragma unroll
      for (int kk = 0; kk < 4; ++kk) {
        const float g = (kk == 0) ? g4.x : (kk == 1) ? g4.y : (kk == 2) ? g4.z : g4.w;
#pragma unroll
        for (int d = 0; d < 8; ++d)
          acc[e][d] = fmaf(W[d + kk], g, acc[e][d]);
      }
      A0[e] = A1[e]; A1[e] = A2;
    }
  }
  // epilogue: red = (ksum - (S-dl)*et)/dl, pairwise |diff| sums
  float etv[8];
  {
    float4 e0 = *(const float4*)(et + 8 * tid);
    float4 e1 = *(const float4*)(et + 8 * tid + 4);
    etv[0] = e0.x; etv[1] = e0.y; etv[2] = e0.z; etv[3] = e0.w;
    etv[4] = e1.x; etv[5] = e1.y; etv[6] = e1.z; etv[7] = e1.w;
  }
  float red[E_][8];
#pragma unroll
  for (int e = 0; e < E_; ++e) {
    const float dlv = dl[e * L_ + l];
    const float zc = (float)S_ - dlv;
    const float idl = 1.0f / dlv;
#pragma unroll
    for (int d = 0; d < 8; ++d)
      red[e][d] = (acc[e][d] - zc * etv[d]) * idl;
  }
  float D[6];
  const int pa[6] = {0, 0, 0, 1, 1, 2};
  const int pb[6] = {1, 2, 3, 2, 3, 3};
#pragma unroll
  for (int p = 0; p < 6; ++p) {
    float s = 0.f;
#pragma unroll
    for (int d = 0; d < 8; ++d) s += fabsf(red[pa[p]][d] - red[pb[p]][d]);
    D[p] = s;
  }
#pragma unroll
  for (int off = 32; off; off >>= 1)
#pragma unroll
    for (int p = 0; p < 6; ++p) D[p] += __shfl_down(D[p], off);
  if ((tid & 63) == 0) {
#pragma unroll
    for (int p = 0; p < 6; ++p) rs[tid >> 6][p] = D[p];
  }
  __syncthreads();
  if (tid == 0) {
    float Tp[6];
#pragma unroll
    for (int p = 0; p < 6; ++p) Tp[p] = (rs[0][p] + rs[1][p]) * scale;
    float test = Tp[0];
#pragma unroll
    for (int p = 1; p < 6; ++p) test = fmaxf(test, Tp[p]);
    float train = fmaxf(fmaxf(Tp[1], Tp[2]), Tp[5]);
    out[l * F_ + f] = train;                 // train_results
    out[L_ * F_ + l * F_ + f] = test;        // test_results
  }
}

extern "C" void kernel_launch(void* const* d_in, const int* in_sizes, int n_in,
                              void* d_out, int out_size, void* d_ws, size_t ws_size,
                              hipStream_t stream) {
  const float* A  = (const float*)d_in[0];   // matrix (4,10,1024,256)
  const float* dl = (const float*)d_in[1];   // data_len (4,10)
  const float* P  = (const float*)d_in[2];   // params (256,256)
  float* out = (float*)d_out;
  float* ws = (float*)d_ws;
  float* hdr = ws;
  int* hdri = (int*)d_ws;
  unsigned int* slots = (unsigned int*)(ws + 16);
  float* Gs = ws + OFF_GS;
  float* et = ws + OFF_ET;
  float* M  = ws + OFF_M;
  float* wb = ws + OFF_W;

  (void)hipMemsetAsync(slots, 0xFF, 4, stream);      // min slot neutral
  (void)hipMemsetAsync(slots + 1, 0x00, 4, stream);  // max slot neutral

  k0_gemm<<<NROW / 64, 256, 0, stream>>>(A, P, M, slots);
  k1_setup<<<1, 256, 0, stream>>>(slots, hdr, hdri, Gs, et);
  k2_bin<<<(E_ * L_) * (F_ / 16), 256, 0, stream>>>(M, hdr, wb);
  k3_conv<<<L_ * F_, 128, 0, stream>>>(wb, Gs, et, hdr, hdri, dl, out);
}